// Round 3
// baseline (169.478 us; speedup 1.0000x reference)
//
#include <hip/hip_runtime.h>
#include <hip/hip_bf16.h>

#define NN 4096
#define DD 128
#define CC 20
#define NSPLIT 16
#define CPS (NN / NSPLIT)             // 256 cols per split
#define ROWS_PER_WAVE 16
#define ROWS_PER_BLOCK 64             // 4 waves x 16 rows
#define NSTRIP (NN / ROWS_PER_BLOCK)  // 64
#define BSTRIDE 152                   // ushorts per LDS B row (128 + 24 pad)

typedef __attribute__((ext_vector_type(8))) short short8;
typedef __attribute__((ext_vector_type(4))) float floatx4;

// ---------------- K1: normalize + bf16, CE partials, zero stats/ctrl ----------------
__global__ void k_prep(const float* __restrict__ x, const float* __restrict__ pred,
                       const int* __restrict__ tgt,
                       __hip_bfloat16* __restrict__ feats,
                       float* __restrict__ statsz,   // 4*NN floats, zeroed here
                       int* __restrict__ ctrlz,      // 80 floats bins + 64 int tickets
                       float* __restrict__ ce_part) {
    __shared__ float ce_w[4];
    int wave = threadIdx.x >> 6, lane = threadIdx.x & 63;
    int row = blockIdx.x * 4 + wave;
    // zero the 4 stat arrays: 1024 blocks x 16 floats = 16384 = 4*4096
    if (threadIdx.x < 16) statsz[blockIdx.x * 16 + threadIdx.x] = 0.0f;
    // zero class bins (80 floats) + tickets (64 ints); consumed only by K2 (stream-ordered)
    if (blockIdx.x == 0 && threadIdx.x < 144) ctrlz[threadIdx.x] = 0;
    // row-normalize cls_feats -> bf16
    const float* xr = x + (size_t)row * DD;
    float2 v = *(const float2*)(xr + lane * 2);
    float ss = v.x * v.x + v.y * v.y;
    #pragma unroll
    for (int m = 1; m <= 32; m <<= 1) ss += __shfl_xor(ss, m);
    float inv = 1.0f / fmaxf(sqrtf(ss), 1e-12f);
    __hip_bfloat162 h;
    h.x = __float2bfloat16(v.x * inv);
    h.y = __float2bfloat16(v.y * inv);
    *(__hip_bfloat162*)(feats + (size_t)row * DD + lane * 2) = h;
    // CE for predicts row (lanes 0..19 hold logits)
    float p = (lane < CC) ? pred[(size_t)row * CC + lane] : -__builtin_inff();
    float mx = p;
    #pragma unroll
    for (int m = 1; m <= 32; m <<= 1) mx = fmaxf(mx, __shfl_xor(mx, m));
    float e = (lane < CC) ? __expf(p - mx) : 0.0f;
    #pragma unroll
    for (int m = 1; m <= 32; m <<= 1) e += __shfl_xor(e, m);
    float ptg = __shfl(p, tgt[row]);
    if (lane == 0) ce_w[wave] = mx + logf(e) - ptg;
    __syncthreads();
    if (threadIdx.x == 0)
        ce_part[blockIdx.x] = ce_w[0] + ce_w[1] + ce_w[2] + ce_w[3];
}

// ---------------- K2: fused Gram + per-row stats + split-K ticket fixup ----------------
// Per row i: E1 = sum_{same,j!=i} exp(10G-10), T1 = sum 10G
//            m2 = max(0, max_diff 20G), E2 = sum_diff exp(20G-20)  [fixed ref]
// Last split-block per strip folds rows into per-class bins:
//   clT[k]+=T1, clL[k]+=10+log(E1), RtA[k]+=exp(-m2), RtB[k]+=E2*exp(20-m2)
__launch_bounds__(256, 4)
__global__ void k_gram_stats(const __hip_bfloat16* __restrict__ feats,
                             const int* __restrict__ tgt,
                             float* __restrict__ E1g, float* __restrict__ T1g,
                             float* __restrict__ E2g, float* __restrict__ M2g,
                             float* __restrict__ bins, int* __restrict__ done) {
    __shared__ __align__(16) unsigned short Bt[64 * BSTRIDE];
    __shared__ int s_old;
    int lane  = threadIdx.x & 63;
    int wave  = threadIdx.x >> 6;
    int strip = blockIdx.x & (NSTRIP - 1);
    int split = blockIdx.x >> 6;
    int rbase  = strip * ROWS_PER_BLOCK + wave * ROWS_PER_WAVE;
    int cbase0 = split * CPS;
    int lr = lane & 15, lk = lane >> 4;

    // A fragments: rows rbase+lr, k = kc*32 + lk*8 + j (same map as B -> valid)
    short8 afrag[4];
    const __hip_bfloat16* arow = feats + (size_t)(rbase + lr) * DD;
    #pragma unroll
    for (int kc = 0; kc < 4; ++kc)
        afrag[kc] = *(const short8*)(arow + kc * 32 + lk * 8);

    int rl[4], gr[4];
    #pragma unroll
    for (int q = 0; q < 4; ++q) { gr[q] = rbase + lk * 4 + q; rl[q] = tgt[gr[q]]; }

    float E1[4] = {0,0,0,0}, T1[4] = {0,0,0,0}, E2[4] = {0,0,0,0}, m2[4] = {0,0,0,0};

    for (int t = 0; t < CPS / 64; ++t) {
        int cbase = cbase0 + t * 64;
        // stage B tile: 64 rows x 128 k bf16, 4 passes of 256 threads x 16B
        #pragma unroll
        for (int i = 0; i < 4; ++i) {
            int idx = threadIdx.x + i * 256;
            int row = idx >> 4, ch = idx & 15;
            *(floatx4*)(&Bt[row * BSTRIDE + ch * 8]) =
                *(const floatx4*)(feats + (size_t)(cbase + row) * DD + ch * 8);
        }
        __syncthreads();
        #pragma unroll
        for (int sc = 0; sc < 4; ++sc) {
            floatx4 acc = {0.0f, 0.0f, 0.0f, 0.0f};
            #pragma unroll
            for (int kc = 0; kc < 4; ++kc) {
                short8 b = *(const short8*)(&Bt[(sc * 16 + lr) * BSTRIDE + kc * 32 + lk * 8]);
                acc = __builtin_amdgcn_mfma_f32_16x16x32_bf16(afrag[kc], b, acc, 0, 0, 0);
            }
            int gc   = cbase + sc * 16 + lr;
            int clab = tgt[gc];
            #pragma unroll
            for (int q = 0; q < 4; ++q) {
                float g  = acc[q];
                float l1 = g * 10.0f;
                float tv = __expf(l1 - 10.0f);
                bool same = (rl[q] == clab);
                bool v1   = same && (gr[q] != gc);
                E1[q] += v1 ? tv : 0.0f;
                T1[q] += v1 ? l1 : 0.0f;
                E2[q] += same ? 0.0f : tv * tv;
                m2[q] = fmaxf(m2[q], same ? 0.0f : l1 + l1);
            }
        }
        __syncthreads();
    }

    // merge across the 16 lanes (lr) of each row-group; then global atomics
    #pragma unroll
    for (int q = 0; q < 4; ++q) {
        float e1 = E1[q], t1 = T1[q], e2 = E2[q], mm = m2[q];
        #pragma unroll
        for (int m = 1; m <= 8; m <<= 1) {
            e1 += __shfl_xor(e1, m);
            t1 += __shfl_xor(t1, m);
            e2 += __shfl_xor(e2, m);
            mm = fmaxf(mm, __shfl_xor(mm, m));
        }
        if (lr == 0) {
            int r = gr[q];
            atomicAdd(&E1g[r], e1);
            atomicAdd(&T1g[r], t1);
            atomicAdd(&E2g[r], e2);
            atomicMax((int*)&M2g[r], __float_as_int(mm));  // mm >= 0: int-bit order ok
        }
    }

    // ---- ticket: last split-block for this strip folds rows into class bins ----
    __threadfence();
    __syncthreads();
    if (threadIdx.x == 0) s_old = atomicAdd(&done[strip], 1);
    __syncthreads();
    if (s_old == NSPLIT - 1 && threadIdx.x < ROWS_PER_BLOCK) {
        __threadfence();
        int r  = strip * ROWS_PER_BLOCK + threadIdx.x;
        int tg = tgt[r];
        // read back via atomic RMW (coherent across XCDs; all writers were atomics)
        float e1 = atomicAdd(&E1g[r], 0.0f);
        float t1 = atomicAdd(&T1g[r], 0.0f);
        float e2 = atomicAdd(&E2g[r], 0.0f);
        float m  = __int_as_float(atomicMax((int*)&M2g[r], 0));
        float* clT = bins;
        float* clL = bins + CC;
        float* RtA = bins + 2 * CC;
        float* RtB = bins + 3 * CC;
        atomicAdd(&clT[tg], t1);
        atomicAdd(&clL[tg], 10.0f + logf(e1));      // -inf iff class size 1; skipped in K3
        atomicAdd(&RtA[tg], __expf(-m));
        atomicAdd(&RtB[tg], e2 * __expf(20.0f - m));
    }
}

// ---------------- K3: class-level finalize (single small block) ----------------
#define FT 256
__global__ void k_finalize(const int* __restrict__ tgt,
                           const float* __restrict__ bins,
                           const float* __restrict__ ce_part, float* __restrict__ out) {
    __shared__ int   hist[CC];
    __shared__ float red[FT];
    int t = threadIdx.x;
    if (t < CC) hist[t] = 0;
    __syncthreads();
    for (int r = t; r < NN; r += FT) atomicAdd(&hist[tgt[r]], 1);
    float cesum = 0.0f;
    for (int i = t; i < 1024; i += FT) cesum += ce_part[i];
    red[t] = cesum; __syncthreads();
    for (int off = FT / 2; off; off >>= 1) {
        if (t < off) red[t] += red[t + off];
        __syncthreads();
    }
    if (t == 0) {
        const float* clT = bins;
        const float* clL = bins + CC;
        const float* RtA = bins + 2 * CC;
        const float* RtB = bins + 3 * CC;
        float ce = red[0] / (float)NN;
        float clsum = 0.0f;
        float Rt[CC];
        float Rtot = 0.0f;
        long long Ctot = 0;
        for (int k = 0; k < CC; ++k) {
            int h = hist[k];
            if (h > 1) clsum += clT[k] / (float)(h - 1) - clL[k];
            Rt[k] = (float)h * RtA[k] + RtB[k];
            Rtot += Rt[k];
            Ctot += (long long)h * (NN - h);
        }
        float cl = -clsum / (float)NN;
        bool all_zero = true;
        for (int k = 0; k < CC; ++k)
            if (hist[k] > 0 && (Ctot - (long long)hist[k] * (NN - hist[k])) != 0) all_zero = false;
        float trip = 0.0f;
        for (int k = 0; k < CC; ++k) {
            if (hist[k] == 0) continue;
            long long c = NN - hist[k];
            float S = (c > 0) ? (Rtot - Rt[k] + (float)hist[k] * (float)NN) : 0.0f;
            long long ns = Ctot - (long long)hist[k] * (NN - hist[k]);
            float x = all_zero ? S : S / (float)(ns == 0 ? 1 : ns);
            trip += (float)hist[k] * logf(x + 1e-12f);
        }
        float triple = trip / (float)NN;
        out[0] = 0.5f * ce + 0.5f * cl + 0.25f * triple;
    }
}

extern "C" void kernel_launch(void* const* d_in, const int* in_sizes, int n_in,
                              void* d_out, int out_size, void* d_ws, size_t ws_size,
                              hipStream_t stream) {
    const float* cls  = (const float*)d_in[0];
    const float* pred = (const float*)d_in[1];
    const int*   tgt  = (const int*)d_in[2];
    float* out = (float*)d_out;
    char* ws = (char*)d_ws;

    __hip_bfloat16* feats = (__hip_bfloat16*)ws;            // 1 MB
    float* stats = (float*)(ws + 1048576);                  // 4*4096 floats
    float* E1g = stats;
    float* T1g = stats + NN;
    float* E2g = stats + 2 * NN;
    float* M2g = stats + 3 * NN;
    float* ce_part = stats + 4 * NN;                        // 1024 floats
    float* bins = ce_part + 1024;                           // 80 floats (clT,clL,RtA,RtB)
    int*   done = (int*)(bins + 4 * CC);                    // 64 tickets

    hipLaunchKernelGGL(k_prep, dim3(NN / 4), dim3(256), 0, stream,
                       cls, pred, tgt, feats, stats, (int*)bins, ce_part);
    hipLaunchKernelGGL(k_gram_stats, dim3(NSTRIP * NSPLIT), dim3(256), 0, stream,
                       feats, tgt, E1g, T1g, E2g, M2g, bins, done);
    hipLaunchKernelGGL(k_finalize, dim3(1), dim3(FT), 0, stream,
                       tgt, bins, ce_part, out);
}

// Round 4
// 87.665 us; speedup vs baseline: 1.9332x; 1.9332x over previous
//
#include <hip/hip_runtime.h>
#include <hip/hip_bf16.h>

#define NN 4096
#define DD 128
#define CC 20
#define NSPLIT 16
#define CPS (NN / NSPLIT)             // 256 cols per split
#define ROWS_PER_WAVE 16
#define ROWS_PER_BLOCK 64             // 4 waves x 16 rows
#define NSTRIP (NN / ROWS_PER_BLOCK)  // 64
#define BSTRIDE 136                   // ushorts per LDS B row (128 + 8 pad; dword stride 68 = 4 mod 32)

typedef __attribute__((ext_vector_type(8))) short short8;
typedef __attribute__((ext_vector_type(4))) float floatx4;

// ---------------- K1: normalize + bf16, CE partials, zero stats ----------------
__global__ void k_prep(const float* __restrict__ x, const float* __restrict__ pred,
                       const int* __restrict__ tgt,
                       __hip_bfloat16* __restrict__ feats,
                       float* __restrict__ statsz,   // 4*NN floats, zeroed here
                       float* __restrict__ ce_part) {
    __shared__ float ce_w[4];
    int wave = threadIdx.x >> 6, lane = threadIdx.x & 63;
    int row = blockIdx.x * 4 + wave;
    // zero the 4 stat arrays: 1024 blocks x 16 floats = 16384 = 4*4096
    if (threadIdx.x < 16) statsz[blockIdx.x * 16 + threadIdx.x] = 0.0f;
    // row-normalize cls_feats -> bf16
    const float* xr = x + (size_t)row * DD;
    float2 v = *(const float2*)(xr + lane * 2);
    float ss = v.x * v.x + v.y * v.y;
    #pragma unroll
    for (int m = 1; m <= 32; m <<= 1) ss += __shfl_xor(ss, m);
    float inv = 1.0f / fmaxf(sqrtf(ss), 1e-12f);
    __hip_bfloat162 h;
    h.x = __float2bfloat16(v.x * inv);
    h.y = __float2bfloat16(v.y * inv);
    *(__hip_bfloat162*)(feats + (size_t)row * DD + lane * 2) = h;
    // CE for predicts row (lanes 0..19 hold logits)
    float p = (lane < CC) ? pred[(size_t)row * CC + lane] : -__builtin_inff();
    float mx = p;
    #pragma unroll
    for (int m = 1; m <= 32; m <<= 1) mx = fmaxf(mx, __shfl_xor(mx, m));
    float e = (lane < CC) ? __expf(p - mx) : 0.0f;
    #pragma unroll
    for (int m = 1; m <= 32; m <<= 1) e += __shfl_xor(e, m);
    float ptg = __shfl(p, tgt[row]);
    if (lane == 0) ce_w[wave] = mx + logf(e) - ptg;
    __syncthreads();
    if (threadIdx.x == 0)
        ce_part[blockIdx.x] = ce_w[0] + ce_w[1] + ce_w[2] + ce_w[3];
}

// ---------------- K2: fused Gram + per-row stats ----------------
// Per row i: E1 = sum_{same,j!=i} exp(10G-10), Tp = sum_{same,j!=i} G (scaled x10 at merge)
//            gm = max_{diff} G (clamped max(0,20*gm) at merge), E2 = sum_diff exp(20G-20)
// exp(20G-20) = exp(10G-10)^2 -> single exp per element. No fences, no tickets.
__launch_bounds__(256, 4)
__global__ void k_gram_stats(const __hip_bfloat16* __restrict__ feats,
                             const int* __restrict__ tgt,
                             float* __restrict__ E1g, float* __restrict__ T1g,
                             float* __restrict__ E2g, float* __restrict__ M2g) {
    __shared__ __align__(16) unsigned short Bt[64 * BSTRIDE];
    int lane  = threadIdx.x & 63;
    int wave  = threadIdx.x >> 6;
    int strip = blockIdx.x & (NSTRIP - 1);
    int split = blockIdx.x >> 6;
    int rbase  = strip * ROWS_PER_BLOCK + wave * ROWS_PER_WAVE;
    int cbase0 = split * CPS;
    int lr = lane & 15, lk = lane >> 4;

    // A fragments: rows rbase+lr, k = kc*32 + lk*8 + j (same map as B -> valid)
    short8 afrag[4];
    const __hip_bfloat16* arow = feats + (size_t)(rbase + lr) * DD;
    #pragma unroll
    for (int kc = 0; kc < 4; ++kc)
        afrag[kc] = *(const short8*)(arow + kc * 32 + lk * 8);

    int rl[4], gr[4];
    #pragma unroll
    for (int q = 0; q < 4; ++q) { gr[q] = rbase + lk * 4 + q; rl[q] = tgt[gr[q]]; }

    float E1[4] = {0,0,0,0}, Tp[4] = {0,0,0,0}, E2[4] = {0,0,0,0};
    float gm[4] = {-2.0f,-2.0f,-2.0f,-2.0f};

    for (int t = 0; t < CPS / 64; ++t) {
        int cbase = cbase0 + t * 64;
        // stage B tile: 64 rows x 128 k bf16, 4 passes of 256 threads x 16B
        #pragma unroll
        for (int i = 0; i < 4; ++i) {
            int idx = threadIdx.x + i * 256;
            int row = idx >> 4, ch = idx & 15;
            *(floatx4*)(&Bt[row * BSTRIDE + ch * 8]) =
                *(const floatx4*)(feats + (size_t)(cbase + row) * DD + ch * 8);
        }
        __syncthreads();
        #pragma unroll
        for (int sc = 0; sc < 4; ++sc) {
            floatx4 acc = {0.0f, 0.0f, 0.0f, 0.0f};
            #pragma unroll
            for (int kc = 0; kc < 4; ++kc) {
                short8 b = *(const short8*)(&Bt[(sc * 16 + lr) * BSTRIDE + kc * 32 + lk * 8]);
                acc = __builtin_amdgcn_mfma_f32_16x16x32_bf16(afrag[kc], b, acc, 0, 0, 0);
            }
            int gc   = cbase + sc * 16 + lr;
            int clab = tgt[gc];
            if (cbase + sc * 16 == rbase) {
                // diagonal tile (wave-uniform branch): exclude j==i from E1/Tp
                #pragma unroll
                for (int q = 0; q < 4; ++q) {
                    float g  = acc[q];
                    float tv = __expf(10.0f * g - 10.0f);
                    bool same = (rl[q] == clab);
                    bool v1   = same && (gr[q] != gc);
                    E1[q] += v1 ? tv : 0.0f;
                    Tp[q] += v1 ? g : 0.0f;
                    E2[q] = same ? E2[q] : fmaf(tv, tv, E2[q]);
                    gm[q] = fmaxf(gm[q], same ? -2.0f : g);
                }
            } else {
                #pragma unroll
                for (int q = 0; q < 4; ++q) {
                    float g  = acc[q];
                    float tv = __expf(10.0f * g - 10.0f);
                    bool same = (rl[q] == clab);
                    E1[q] += same ? tv : 0.0f;
                    Tp[q] += same ? g : 0.0f;
                    E2[q] = same ? E2[q] : fmaf(tv, tv, E2[q]);
                    gm[q] = fmaxf(gm[q], same ? -2.0f : g);
                }
            }
        }
        __syncthreads();
    }

    // merge across the 16 lanes (lr) of each row-group; then global atomics
    #pragma unroll
    for (int q = 0; q < 4; ++q) {
        float e1 = E1[q], tp = Tp[q], e2 = E2[q], mm = gm[q];
        #pragma unroll
        for (int m = 1; m <= 8; m <<= 1) {
            e1 += __shfl_xor(e1, m);
            tp += __shfl_xor(tp, m);
            e2 += __shfl_xor(e2, m);
            mm = fmaxf(mm, __shfl_xor(mm, m));
        }
        if (lr == 0) {
            int r = gr[q];
            atomicAdd(&E1g[r], e1);
            atomicAdd(&T1g[r], 10.0f * tp);
            atomicAdd(&E2g[r], e2);
            // M2g init 0; negative candidates correctly lose to 0 under int compare,
            // which implements the reference's max(0, max_diff 20G) clamp.
            atomicMax((int*)&M2g[r], __float_as_int(20.0f * mm));
        }
    }
}

// ---------------- K3: finalize (single block, 1024 threads) ----------------
#define FT 1024
__global__ void k_finalize(const int* __restrict__ tgt,
                           const float* __restrict__ E1g, const float* __restrict__ T1g,
                           const float* __restrict__ E2g, const float* __restrict__ M2g,
                           const float* __restrict__ ce_part, float* __restrict__ out) {
    __shared__ int   hist[CC];
    __shared__ float Rt[CC];
    __shared__ float red[FT];
    __shared__ float s_cl;
    int t = threadIdx.x;
    if (t < CC) { hist[t] = 0; Rt[t] = 0.0f; }
    __syncthreads();
    for (int r = t; r < NN; r += FT) atomicAdd(&hist[tgt[r]], 1);
    __syncthreads();

    float clsum = 0.0f;
    for (int r = t; r < NN; r += FT) {
        int tg = tgt[r];
        int h  = hist[tg];
        float e1 = E1g[r], t1 = T1g[r], e2 = E2g[r], m = M2g[r];
        if (h > 1) clsum += t1 / (float)(h - 1) - (10.0f + logf(e1));
        float rj = (float)h * __expf(-m) + e2 * __expf(20.0f - m);
        atomicAdd(&Rt[tg], rj);
    }
    float cesum = ce_part[t];  // 1024 entries, one per thread

    red[t] = clsum; __syncthreads();
    for (int off = FT / 2; off; off >>= 1) {
        if (t < off) red[t] += red[t + off];
        __syncthreads();
    }
    if (t == 0) s_cl = red[0];
    __syncthreads();
    red[t] = cesum; __syncthreads();
    for (int off = FT / 2; off; off >>= 1) {
        if (t < off) red[t] += red[t + off];
        __syncthreads();
    }
    if (t == 0) {
        float ce = red[0] / (float)NN;
        float cl = -s_cl / (float)NN;
        float Rtot = 0.0f;
        long long Ctot = 0;
        float Rtv[CC];
        for (int k = 0; k < CC; ++k) {
            Rtv[k] = Rt[k];
            Rtot += Rtv[k];
            Ctot += (long long)hist[k] * (NN - hist[k]);
        }
        bool all_zero = true;
        for (int k = 0; k < CC; ++k)
            if (hist[k] > 0 && (Ctot - (long long)hist[k] * (NN - hist[k])) != 0) all_zero = false;
        float trip = 0.0f;
        for (int k = 0; k < CC; ++k) {
            if (hist[k] == 0) continue;
            long long c = NN - hist[k];
            float S = (c > 0) ? (Rtot - Rtv[k] + (float)hist[k] * (float)NN) : 0.0f;
            long long ns = Ctot - (long long)hist[k] * (NN - hist[k]);
            float x = all_zero ? S : S / (float)(ns == 0 ? 1 : ns);
            trip += (float)hist[k] * logf(x + 1e-12f);
        }
        float triple = trip / (float)NN;
        out[0] = 0.5f * ce + 0.5f * cl + 0.25f * triple;
    }
}

extern "C" void kernel_launch(void* const* d_in, const int* in_sizes, int n_in,
                              void* d_out, int out_size, void* d_ws, size_t ws_size,
                              hipStream_t stream) {
    const float* cls  = (const float*)d_in[0];
    const float* pred = (const float*)d_in[1];
    const int*   tgt  = (const int*)d_in[2];
    float* out = (float*)d_out;
    char* ws = (char*)d_ws;

    __hip_bfloat16* feats = (__hip_bfloat16*)ws;            // 1 MB
    float* stats = (float*)(ws + 1048576);                  // 4*4096 floats
    float* E1g = stats;
    float* T1g = stats + NN;
    float* E2g = stats + 2 * NN;
    float* M2g = stats + 3 * NN;
    float* ce_part = stats + 4 * NN;                        // 1024 floats

    hipLaunchKernelGGL(k_prep, dim3(NN / 4), dim3(256), 0, stream,
                       cls, pred, tgt, feats, stats, ce_part);
    hipLaunchKernelGGL(k_gram_stats, dim3(NSTRIP * NSPLIT), dim3(256), 0, stream,
                       feats, tgt, E1g, T1g, E2g, M2g);
    hipLaunchKernelGGL(k_finalize, dim3(1), dim3(FT), 0, stream,
                       tgt, E1g, T1g, E2g, M2g, ce_part, out);
}